// Round 4
// baseline (1278.089 us; speedup 1.0000x reference)
//
#include <hip/hip_runtime.h>

#define DI __device__ __forceinline__

typedef unsigned int uint;
typedef unsigned short ushort;
typedef _Float16 half2t __attribute__((ext_vector_type(2)));
typedef _Float16 half4t __attribute__((ext_vector_type(4)));

#define VOCAB 50257
#define NEMB 48
#define HID 128
#define G4 512
#define NCLS 2000
#define BATCH 512
#define SEQ 1024

#if __has_builtin(__builtin_amdgcn_fdot2)
DI float fdot2(half2t a, half2t b, float c) { return __builtin_amdgcn_fdot2(a, b, c, false); }
#else
DI float fdot2(half2t a, half2t b, float c) { return c + (float)a.x * (float)b.x + (float)a.y * (float)b.y; }
#endif

DI float sigm(float x) {
  return __builtin_amdgcn_rcpf(1.0f + __builtin_amdgcn_exp2f(-1.4426950408889634f * x));
}
DI float tanhfast(float x) {
  return 1.0f - 2.0f * __builtin_amdgcn_rcpf(__builtin_amdgcn_exp2f(2.8853900817779268f * x) + 1.0f);
}

// VALU-pipe cross-lane: swap with lane^1 via DPP quad_perm(1,0,3,2)=0xB1.
DI float dppx1(float v) {
  return __builtin_bit_cast(float,
      __builtin_amdgcn_update_dpp(0, __builtin_bit_cast(int, v), 0xB1, 0xF, 0xF, true));
}

// ---------------------------------------------------------------------------
// Phase A: P2[v][u][g] = emb[v].w_ih[g*128+u] + b_ih[..] + b_hh[..], f16.
// Gate-interleaved layout so the scan's xg gather is ONE b64 per thread.
// ---------------------------------------------------------------------------
#define VROWS 32
__global__ __launch_bounds__(512) void build_P(
    const float* __restrict__ emb, const float* __restrict__ w_ih,
    const float* __restrict__ b_ih, const float* __restrict__ b_hh,
    ushort* __restrict__ P2)
{
  __shared__ __align__(16) float eL[VROWS][NEMB];
  __shared__ ushort pg[VROWS][G4];
  const int tid = threadIdx.x;
  const int v0 = blockIdx.x * VROWS;
  int nrows = VOCAB - v0; if (nrows > VROWS) nrows = VROWS;

  for (int f = tid; f < nrows * NEMB; f += 512)
    eL[f / NEMB][f % NEMB] = emb[(size_t)v0 * NEMB + f];

  float wv[NEMB];
  {
    const float* wr = w_ih + (size_t)tid * NEMB;
#pragma unroll
    for (int k = 0; k < NEMB; k++) wv[k] = wr[k];
  }
  float bias = b_ih[tid] + b_hh[tid];
  __syncthreads();

  for (int v = 0; v < nrows; v++) {
    const float4* e4 = (const float4*)&eL[v][0];
    float a = bias;
#pragma unroll
    for (int k = 0; k < NEMB / 4; k++) {
      float4 e = e4[k];
      a += wv[4 * k] * e.x + wv[4 * k + 1] * e.y + wv[4 * k + 2] * e.z + wv[4 * k + 3] * e.w;
    }
    pg[v][tid] = __builtin_bit_cast(ushort, (_Float16)a);
  }
  __syncthreads();
  // repack cols (g*128+u) -> [u][g], coalesced uint2 stores
  for (int f = tid; f < nrows * (G4 / 4); f += 512) {
    int v = f >> 7, u = f & 127;
    uint2 pk;
    pk.x = (uint)pg[v][u]       | ((uint)pg[v][u + 128] << 16);
    pk.y = (uint)pg[v][u + 256] | ((uint)pg[v][u + 384] << 16);
    ((uint2*)(P2 + (size_t)(v0 + v) * G4))[u] = pk;
  }
}

// ---------------------------------------------------------------------------
// Phase B: persistent LSTM scan. 512 blocks x 128 threads (1 row/block,
// 2 blocks/CU). Thread tid owns ALL 4 gates of unit tid (in-lane gates, no
// g-matrix LDS roundtrip; c in VGPR). Lane pairs split the k-range: even
// lane dots k=0..63, odd k=64..127, for both units' 8 gate-cols; partials
// combined via DPP xor-1 (VALU pipe). h broadcast: 8 ds_read_b128/thread.
// Double-buffered h16 -> 1 barrier/step. xg: one b64 gather from P2,
// prefetched 2 steps ahead.
// ---------------------------------------------------------------------------
template<bool USE_P>
__global__ __launch_bounds__(128, 1) void lstm_scan(
    const int* __restrict__ x, const float* __restrict__ emb,
    const float* __restrict__ w_ih, const float* __restrict__ w_hh,
    const float* __restrict__ b_ih, const float* __restrict__ b_hh,
    const ushort* __restrict__ P2, float* __restrict__ hout)
{
  __shared__ int tokL[SEQ];
  __shared__ __align__(16) _Float16 h16[2][HID];
  __shared__ __align__(8) half2t e16[2][NEMB / 2];

  const int tid = threadIdx.x;
  const int b   = blockIdx.x;
  const int sub = tid & 1;       // k-half selector
  const int u0  = tid & ~1;      // unit pair base

  {
    const int* xp = x + (size_t)b * SEQ;
#pragma unroll
    for (int i = 0; i < SEQ / 128; i++) tokL[tid + 128 * i] = xp[tid + 128 * i];
  }

  // W_hh fragments: 8 cols {u0,u0+1} x gates{i,f,g,o}, k in [64*sub, 64*sub+64)
  // 8 cols x 32 half2 = 128 VGPRs
  half2t w[8][32];
#pragma unroll
  for (int g = 0; g < 4; g++)
#pragma unroll
    for (int cc = 0; cc < 2; cc++) {
      const float4* wr = (const float4*)(w_hh + (size_t)(g * HID + u0 + cc) * HID + 64 * sub);
#pragma unroll
      for (int k4 = 0; k4 < 16; k4++) {
        float4 v = wr[k4];
        half2t p;
        p.x = (_Float16)v.x; p.y = (_Float16)v.y; w[2 * g + cc][2 * k4] = p;
        p.x = (_Float16)v.z; p.y = (_Float16)v.w; w[2 * g + cc][2 * k4 + 1] = p;
      }
    }

  half2t wih[4][NEMB / 2];
  float biasg[4] = {0.f, 0.f, 0.f, 0.f};
  if (!USE_P) {
#pragma unroll
    for (int g = 0; g < 4; g++) {
      const float* wr = w_ih + (size_t)(g * HID + tid) * NEMB;
#pragma unroll
      for (int k = 0; k < NEMB / 2; k++) {
        half2t p; p.x = (_Float16)wr[2 * k]; p.y = (_Float16)wr[2 * k + 1];
        wih[g][k] = p;
      }
      biasg[g] = b_ih[g * HID + tid] + b_hh[g * HID + tid];
    }
  }
  h16[1][tid] = (_Float16)0.0f;   // step 0 reads buf 1
  __syncthreads();                // tokens + h16[1] visible

  float c = 0.0f;
  uint2 pa{0, 0}, pb{0, 0};
  float2 einfl = {0.0f, 0.0f};
  if (USE_P) {
    pa = ((const uint2*)(P2 + (size_t)tokL[0] * G4))[tid];
    pb = ((const uint2*)(P2 + (size_t)tokL[1] * G4))[tid];
  } else {
    if (tid < NEMB / 2) {
      float2 e0 = ((const float2*)(emb + (size_t)tokL[0] * NEMB))[tid];
      einfl     = ((const float2*)(emb + (size_t)tokL[1] * NEMB))[tid];
      half2t p; p.x = (_Float16)e0.x; p.y = (_Float16)e0.y;
      e16[0][tid] = p;
    }
    __syncthreads();
  }

#define STEP(t, par) do {                                                      \
    int tc = (t) + 2; if (tc > SEQ - 1) tc = SEQ - 1;                          \
    int tn = tokL[tc];                                                         \
    uint2 cur = (par) ? pb : pa;                                               \
    if (USE_P) {                                                               \
      uint2 nx = ((const uint2*)(P2 + (size_t)tn * G4))[tid]; /* t+2 */        \
      if ((par) == 0) pa = nx; else pb = nx;                                   \
    } else {                                                                   \
      if (tid < NEMB / 2) {                                                    \
        half2t p; p.x = (_Float16)einfl.x; p.y = (_Float16)einfl.y;            \
        e16[((t) + 1) & 1][tid] = p;                                           \
        einfl = ((const float2*)(emb + (size_t)tn * NEMB))[tid];               \
      }                                                                        \
    }                                                                          \
    const uint4* hv = (const uint4*)((const _Float16*)h16[(par) ^ 1] + 64 * sub);\
    float a0=0,a1=0,a2=0,a3=0,a4=0,a5=0,a6=0,a7=0;                             \
    _Pragma("unroll")                                                          \
    for (int q = 0; q < 8; q++) {                                              \
      uint4 hq = hv[q];                                                        \
      half2t h0 = __builtin_bit_cast(half2t, hq.x);                            \
      half2t h1 = __builtin_bit_cast(half2t, hq.y);                            \
      half2t h2 = __builtin_bit_cast(half2t, hq.z);                            \
      half2t h3 = __builtin_bit_cast(half2t, hq.w);                            \
      a0=fdot2(w[0][4*q],h0,a0); a1=fdot2(w[1][4*q],h0,a1);                    \
      a2=fdot2(w[2][4*q],h0,a2); a3=fdot2(w[3][4*q],h0,a3);                    \
      a4=fdot2(w[4][4*q],h0,a4); a5=fdot2(w[5][4*q],h0,a5);                    \
      a6=fdot2(w[6][4*q],h0,a6); a7=fdot2(w[7][4*q],h0,a7);                    \
      a0=fdot2(w[0][4*q+1],h1,a0); a1=fdot2(w[1][4*q+1],h1,a1);                \
      a2=fdot2(w[2][4*q+1],h1,a2); a3=fdot2(w[3][4*q+1],h1,a3);                \
      a4=fdot2(w[4][4*q+1],h1,a4); a5=fdot2(w[5][4*q+1],h1,a5);                \
      a6=fdot2(w[6][4*q+1],h1,a6); a7=fdot2(w[7][4*q+1],h1,a7);                \
      a0=fdot2(w[0][4*q+2],h2,a0); a1=fdot2(w[1][4*q+2],h2,a1);                \
      a2=fdot2(w[2][4*q+2],h2,a2); a3=fdot2(w[3][4*q+2],h2,a3);                \
      a4=fdot2(w[4][4*q+2],h2,a4); a5=fdot2(w[5][4*q+2],h2,a5);                \
      a6=fdot2(w[6][4*q+2],h2,a6); a7=fdot2(w[7][4*q+2],h2,a7);                \
      a0=fdot2(w[0][4*q+3],h3,a0); a1=fdot2(w[1][4*q+3],h3,a1);                \
      a2=fdot2(w[2][4*q+3],h3,a2); a3=fdot2(w[3][4*q+3],h3,a3);                \
      a4=fdot2(w[4][4*q+3],h3,a4); a5=fdot2(w[5][4*q+3],h3,a5);                \
      a6=fdot2(w[6][4*q+3],h3,a6); a7=fdot2(w[7][4*q+3],h3,a7);                \
    }                                                                          \
    float f0 = a0 + dppx1(a0), f1 = a1 + dppx1(a1);                            \
    float f2 = a2 + dppx1(a2), f3 = a3 + dppx1(a3);                            \
    float f4 = a4 + dppx1(a4), f5 = a5 + dppx1(a5);                            \
    float f6 = a6 + dppx1(a6), f7 = a7 + dppx1(a7);                            \
    float xgi, xgf, xgg, xgo;                                                  \
    if (USE_P) {                                                               \
      half4t xv = __builtin_bit_cast(half4t, cur);                             \
      xgi = (float)xv.x; xgf = (float)xv.y; xgg = (float)xv.z; xgo = (float)xv.w;\
    } else {                                                                   \
      xgi = biasg[0]; xgf = biasg[1]; xgg = biasg[2]; xgo = biasg[3];          \
      _Pragma("unroll")                                                        \
      for (int k = 0; k < NEMB / 2; k++) {                                     \
        half2t ev = e16[(par)][k];                                             \
        xgi = fdot2(wih[0][k], ev, xgi); xgf = fdot2(wih[1][k], ev, xgf);      \
        xgg = fdot2(wih[2][k], ev, xgg); xgo = fdot2(wih[3][k], ev, xgo);      \
      }                                                                        \
    }                                                                          \
    float gi = (sub ? f1 : f0) + xgi;                                          \
    float gf = (sub ? f3 : f2) + xgf;                                          \
    float gc = (sub ? f5 : f4) + xgg;                                          \
    float go = (sub ? f7 : f6) + xgo;                                          \
    float fi = sigm(gi), ff = sigm(gf), gt = tanhfast(gc), fo = sigm(go);      \
    c = ff * c + fi * gt;                                                      \
    float hh = fo * tanhfast(c);                                               \
    h16[(par)][tid] = (_Float16)hh;                                            \
    if ((t) == SEQ - 1) hout[(size_t)b * HID + tid] = hh;                      \
    __syncthreads();                                                           \
  } while (0)

  for (int t = 0; t < SEQ; t += 2) { STEP(t, 0); STEP(t + 1, 1); }
#undef STEP
}

// ---------------------------------------------------------------------------
// Phase C: FC  out[512,2000] = h[512,128] @ w_fc^T + b_fc.  64x64 tiles.
// ---------------------------------------------------------------------------
#define FCR 64
#define FCC 64
__global__ __launch_bounds__(256) void fc_kernel(
    const float* __restrict__ h, const float* __restrict__ w_fc,
    const float* __restrict__ b_fc, float* __restrict__ out)
{
  __shared__ float aT[HID][FCR];
  __shared__ float bT[HID][FCC];
  const int tid = threadIdx.x;
  const int r0 = blockIdx.y * FCR;
  const int c0 = blockIdx.x * FCC;

  for (int f = tid; f < FCR * (HID / 4); f += 256) {
    int row = f >> 5, q = f & 31;
    float4 v = ((const float4*)h)[(((size_t)(r0 + row)) << 5) + q];
    aT[4 * q + 0][row] = v.x; aT[4 * q + 1][row] = v.y;
    aT[4 * q + 2][row] = v.z; aT[4 * q + 3][row] = v.w;
    int wrow = c0 + row;
    float4 wv;
    if (wrow < NCLS) wv = ((const float4*)w_fc)[(((size_t)wrow) << 5) + q];
    else { wv.x = 0.f; wv.y = 0.f; wv.z = 0.f; wv.w = 0.f; }
    bT[4 * q + 0][row] = wv.x; bT[4 * q + 1][row] = wv.y;
    bT[4 * q + 2][row] = wv.z; bT[4 * q + 3][row] = wv.w;
  }
  __syncthreads();

  const int cr = tid & 15, rr = tid >> 4;
  float acc[4][4];
#pragma unroll
  for (int i = 0; i < 4; i++)
#pragma unroll
    for (int j = 0; j < 4; j++) acc[i][j] = 0.0f;

#pragma unroll 4
  for (int k = 0; k < HID; k++) {
    float4 av = *(const float4*)&aT[k][4 * rr];
    float4 bv = *(const float4*)&bT[k][4 * cr];
    float a[4] = {av.x, av.y, av.z, av.w};
    float bb[4] = {bv.x, bv.y, bv.z, bv.w};
#pragma unroll
    for (int i = 0; i < 4; i++)
#pragma unroll
      for (int j = 0; j < 4; j++) acc[i][j] += a[i] * bb[j];
  }

#pragma unroll
  for (int j = 0; j < 4; j++) {
    int cc = c0 + 4 * cr + j;
    if (cc < NCLS) {
      float bias = b_fc[cc];
#pragma unroll
      for (int i = 0; i < 4; i++)
        out[(size_t)(r0 + 4 * rr + i) * NCLS + cc] = acc[i][j] + bias;
    }
  }
}

extern "C" void kernel_launch(void* const* d_in, const int* in_sizes, int n_in,
                              void* d_out, int out_size, void* d_ws, size_t ws_size,
                              hipStream_t stream) {
  const int*   xx   = (const int*)d_in[0];
  const float* emb  = (const float*)d_in[1];
  const float* w_ih = (const float*)d_in[2];
  const float* w_hh = (const float*)d_in[3];
  const float* b_ih = (const float*)d_in[4];
  const float* b_hh = (const float*)d_in[5];
  const float* w_fc = (const float*)d_in[6];
  const float* b_fc = (const float*)d_in[7];
  float* out = (float*)d_out;

  const size_t pbytes = (size_t)VOCAB * G4 * sizeof(ushort); // 51.5 MB
  const size_t palign = (pbytes + 255) & ~(size_t)255;
  const size_t hbytes = (size_t)BATCH * HID * sizeof(float);

  float* hout;
  if (ws_size >= palign + hbytes) {
    ushort* P2 = (ushort*)d_ws;
    hout = (float*)((char*)d_ws + palign);
    build_P<<<(VOCAB + VROWS - 1) / VROWS, 512, 0, stream>>>(emb, w_ih, b_ih, b_hh, P2);
    lstm_scan<true><<<BATCH, 128, 0, stream>>>(xx, emb, w_ih, w_hh, b_ih, b_hh, P2, hout);
  } else {
    hout = (float*)d_ws;
    lstm_scan<false><<<BATCH, 128, 0, stream>>>(xx, emb, w_ih, w_hh, b_ih, b_hh,
                                                (const ushort*)nullptr, hout);
  }
  dim3 fcg((NCLS + FCC - 1) / FCC, BATCH / FCR);
  fc_kernel<<<fcg, 256, 0, stream>>>(hout, w_fc, b_fc, out);
}

// Round 5
// 1167.644 us; speedup vs baseline: 1.0946x; 1.0946x over previous
//
#include <hip/hip_runtime.h>

#define DI __device__ __forceinline__

typedef unsigned int uint;
typedef unsigned short ushort;
typedef _Float16 half2t __attribute__((ext_vector_type(2)));
typedef _Float16 half4t __attribute__((ext_vector_type(4)));

#define VOCAB 50257
#define NEMB 48
#define HID 128
#define G4 512
#define NCLS 2000
#define BATCH 512
#define SEQ 1024

#if __has_builtin(__builtin_amdgcn_fdot2)
DI float fdot2(half2t a, half2t b, float c) { return __builtin_amdgcn_fdot2(a, b, c, false); }
#else
DI float fdot2(half2t a, half2t b, float c) { return c + (float)a.x * (float)b.x + (float)a.y * (float)b.y; }
#endif

DI float sigm(float x) {
  return __builtin_amdgcn_rcpf(1.0f + __builtin_amdgcn_exp2f(-1.4426950408889634f * x));
}
DI float tanhfast(float x) {
  return 1.0f - 2.0f * __builtin_amdgcn_rcpf(__builtin_amdgcn_exp2f(2.8853900817779268f * x) + 1.0f);
}

// VALU-pipe quad butterfly: xor-1 then xor-2 gives full quad sum in all 4 lanes.
DI float dppx1(float v) {
  return __builtin_bit_cast(float,
      __builtin_amdgcn_update_dpp(0, __builtin_bit_cast(int, v), 0xB1, 0xF, 0xF, true));
}
DI float dppx2(float v) {
  return __builtin_bit_cast(float,
      __builtin_amdgcn_update_dpp(0, __builtin_bit_cast(int, v), 0x4E, 0xF, 0xF, true));
}
DI float quadsum(float v) { v += dppx1(v); v += dppx2(v); return v; }

// ---------------------------------------------------------------------------
// Phase A: P2[v][u][g] = emb[v].w_ih[g*128+u] + b_ih[..] + b_hh[..], f16.
// Gate-interleaved so the scan's xg gather is ONE b64 per quad.
// ---------------------------------------------------------------------------
#define VROWS 32
__global__ __launch_bounds__(512) void build_P(
    const float* __restrict__ emb, const float* __restrict__ w_ih,
    const float* __restrict__ b_ih, const float* __restrict__ b_hh,
    ushort* __restrict__ P2)
{
  __shared__ __align__(16) float eL[VROWS][NEMB];
  __shared__ ushort pg[VROWS][G4];
  const int tid = threadIdx.x;
  const int v0 = blockIdx.x * VROWS;
  int nrows = VOCAB - v0; if (nrows > VROWS) nrows = VROWS;

  for (int f = tid; f < nrows * NEMB; f += 512)
    eL[f / NEMB][f % NEMB] = emb[(size_t)v0 * NEMB + f];

  float wv[NEMB];
  {
    const float* wr = w_ih + (size_t)tid * NEMB;
#pragma unroll
    for (int k = 0; k < NEMB; k++) wv[k] = wr[k];
  }
  float bias = b_ih[tid] + b_hh[tid];
  __syncthreads();

  for (int v = 0; v < nrows; v++) {
    const float4* e4 = (const float4*)&eL[v][0];
    float a = bias;
#pragma unroll
    for (int k = 0; k < NEMB / 4; k++) {
      float4 e = e4[k];
      a += wv[4 * k] * e.x + wv[4 * k + 1] * e.y + wv[4 * k + 2] * e.z + wv[4 * k + 3] * e.w;
    }
    pg[v][tid] = __builtin_bit_cast(ushort, (_Float16)a);
  }
  __syncthreads();
  for (int f = tid; f < nrows * (G4 / 4); f += 512) {
    int v = f >> 7, u = f & 127;
    uint2 pk;
    pk.x = (uint)pg[v][u]       | ((uint)pg[v][u + 128] << 16);
    pk.y = (uint)pg[v][u + 256] | ((uint)pg[v][u + 384] << 16);
    ((uint2*)(P2 + (size_t)(v0 + v) * G4))[u] = pk;
  }
}

// ---------------------------------------------------------------------------
// Phase B: persistent LSTM scan. 512 blocks x 512 threads (1 row/block,
// 2 blocks/CU, 4 waves/SIMD). Thread (u = tid>>2, q = tid&3) owns unit u's
// 4 gate rows over k in [32q, 32q+32): 64 fdot2/step, 4 ds_read_b128 (16-lane
// broadcasts). Quad DPP butterfly reduces the k-split; gates computed
// redundantly in all 4 lanes (c replicated in-lane, no LDS round-trip).
// Double-buffered h16 -> 1 barrier/step. xg: one b64 from P2, 2-ahead.
// ---------------------------------------------------------------------------
template<bool USE_P>
__global__ __launch_bounds__(512, 4) void lstm_scan(
    const int* __restrict__ x, const float* __restrict__ emb,
    const float* __restrict__ w_ih, const float* __restrict__ w_hh,
    const float* __restrict__ b_ih, const float* __restrict__ b_hh,
    const ushort* __restrict__ P2, float* __restrict__ hout)
{
  __shared__ int tokL[SEQ];
  __shared__ __align__(16) _Float16 h16[2][HID];
  __shared__ __align__(8) half2t e16[2][NEMB / 2];

  const int tid = threadIdx.x;
  const int b   = blockIdx.x;
  const int u   = tid >> 2;      // unit
  const int q   = tid & 3;       // k-quarter

  {
    const int* xp = x + (size_t)b * SEQ;
    tokL[tid] = xp[tid];
    tokL[tid + 512] = xp[tid + 512];
  }

  // W_hh fragments: gates i,f,g,o of unit u, k in [32q, 32q+32): 64 VGPRs.
  half2t w[4][16];
#pragma unroll
  for (int g = 0; g < 4; g++) {
    const float4* wr = (const float4*)(w_hh + (size_t)(g * HID + u) * HID + 32 * q);
#pragma unroll
    for (int k4 = 0; k4 < 8; k4++) {
      float4 v = wr[k4];
      half2t p;
      p.x = (_Float16)v.x; p.y = (_Float16)v.y; w[g][2 * k4] = p;
      p.x = (_Float16)v.z; p.y = (_Float16)v.w; w[g][2 * k4 + 1] = p;
    }
  }

  // Fallback input-weights: k-split of w_ih over [12q, 12q+12): 24 VGPRs.
  half2t wih[4][6];
  float biasg[4] = {0.f, 0.f, 0.f, 0.f};
  if (!USE_P) {
#pragma unroll
    for (int g = 0; g < 4; g++) {
      const float* wr = w_ih + (size_t)(g * HID + u) * NEMB + 12 * q;
#pragma unroll
      for (int k = 0; k < 6; k++) {
        half2t p; p.x = (_Float16)wr[2 * k]; p.y = (_Float16)wr[2 * k + 1];
        wih[g][k] = p;
      }
      biasg[g] = b_ih[g * HID + u] + b_hh[g * HID + u];
    }
  }
  if (tid < HID) h16[1][tid] = (_Float16)0.0f;   // step 0 reads buf 1
  __syncthreads();

  float c = 0.0f;
  uint2 pa{0, 0}, pb{0, 0};
  float2 einfl = {0.0f, 0.0f};
  if (USE_P) {
    pa = ((const uint2*)(P2 + (size_t)tokL[0] * G4))[u];
    pb = ((const uint2*)(P2 + (size_t)tokL[1] * G4))[u];
  } else {
    if (tid < NEMB / 2) {
      float2 e0 = ((const float2*)(emb + (size_t)tokL[0] * NEMB))[tid];
      einfl     = ((const float2*)(emb + (size_t)tokL[1] * NEMB))[tid];
      half2t p; p.x = (_Float16)e0.x; p.y = (_Float16)e0.y;
      e16[0][tid] = p;
    }
    __syncthreads();
  }

#define STEP(t, par) do {                                                      \
    int tc = (t) + 2; if (tc > SEQ - 1) tc = SEQ - 1;                          \
    int tn = tokL[tc];                                                         \
    uint2 cur = (par) ? pb : pa;                                               \
    float ai = 0.f, af = 0.f, ag = 0.f, ao = 0.f;                              \
    if (USE_P) {                                                               \
      uint2 nx = ((const uint2*)(P2 + (size_t)tn * G4))[u]; /* t+2 */          \
      if ((par) == 0) pa = nx; else pb = nx;                                   \
    } else {                                                                   \
      if (tid < NEMB / 2) {                                                    \
        half2t p; p.x = (_Float16)einfl.x; p.y = (_Float16)einfl.y;            \
        e16[((t) + 1) & 1][tid] = p;                                           \
        einfl = ((const float2*)(emb + (size_t)tn * NEMB))[tid];               \
      }                                                                        \
      _Pragma("unroll")                                                        \
      for (int k = 0; k < 6; k++) {                                            \
        half2t ev = e16[(par)][6 * q + k];                                     \
        ai = fdot2(wih[0][k], ev, ai); af = fdot2(wih[1][k], ev, af);          \
        ag = fdot2(wih[2][k], ev, ag); ao = fdot2(wih[3][k], ev, ao);          \
      }                                                                        \
    }                                                                          \
    const uint4* hv = (const uint4*)(&h16[(par) ^ 1][32 * q]);                 \
    _Pragma("unroll")                                                          \
    for (int q4 = 0; q4 < 4; q4++) {                                           \
      uint4 hq = hv[q4];                                                       \
      half2t h0 = __builtin_bit_cast(half2t, hq.x);                            \
      half2t h1 = __builtin_bit_cast(half2t, hq.y);                            \
      half2t h2 = __builtin_bit_cast(half2t, hq.z);                            \
      half2t h3 = __builtin_bit_cast(half2t, hq.w);                            \
      ai = fdot2(w[0][4*q4+0], h0, ai); af = fdot2(w[1][4*q4+0], h0, af);      \
      ag = fdot2(w[2][4*q4+0], h0, ag); ao = fdot2(w[3][4*q4+0], h0, ao);      \
      ai = fdot2(w[0][4*q4+1], h1, ai); af = fdot2(w[1][4*q4+1], h1, af);      \
      ag = fdot2(w[2][4*q4+1], h1, ag); ao = fdot2(w[3][4*q4+1], h1, ao);      \
      ai = fdot2(w[0][4*q4+2], h2, ai); af = fdot2(w[1][4*q4+2], h2, af);      \
      ag = fdot2(w[2][4*q4+2], h2, ag); ao = fdot2(w[3][4*q4+2], h2, ao);      \
      ai = fdot2(w[0][4*q4+3], h3, ai); af = fdot2(w[1][4*q4+3], h3, af);      \
      ag = fdot2(w[2][4*q4+3], h3, ag); ao = fdot2(w[3][4*q4+3], h3, ao);      \
    }                                                                          \
    float gi = quadsum(ai), gf = quadsum(af);                                  \
    float gc = quadsum(ag), go = quadsum(ao);                                  \
    if (USE_P) {                                                               \
      half4t xv = __builtin_bit_cast(half4t, cur);                             \
      gi += (float)xv.x; gf += (float)xv.y; gc += (float)xv.z; go += (float)xv.w;\
    } else {                                                                   \
      gi += biasg[0]; gf += biasg[1]; gc += biasg[2]; go += biasg[3];          \
    }                                                                          \
    float fi = sigm(gi), ff = sigm(gf), gt = tanhfast(gc), fo = sigm(go);      \
    c = ff * c + fi * gt;                                                      \
    float hh = fo * tanhfast(c);                                               \
    if (q == 0) {                                                              \
      h16[(par)][u] = (_Float16)hh;                                            \
      if ((t) == SEQ - 1) hout[(size_t)b * HID + u] = hh;                      \
    }                                                                          \
    __syncthreads();                                                           \
  } while (0)

  for (int t = 0; t < SEQ; t += 2) { STEP(t, 0); STEP(t + 1, 1); }
#undef STEP
}

// ---------------------------------------------------------------------------
// Phase C: FC  out[512,2000] = h[512,128] @ w_fc^T + b_fc.  64x64 tiles.
// ---------------------------------------------------------------------------
#define FCR 64
#define FCC 64
__global__ __launch_bounds__(256) void fc_kernel(
    const float* __restrict__ h, const float* __restrict__ w_fc,
    const float* __restrict__ b_fc, float* __restrict__ out)
{
  __shared__ float aT[HID][FCR];
  __shared__ float bT[HID][FCC];
  const int tid = threadIdx.x;
  const int r0 = blockIdx.y * FCR;
  const int c0 = blockIdx.x * FCC;

  for (int f = tid; f < FCR * (HID / 4); f += 256) {
    int row = f >> 5, qq = f & 31;
    float4 v = ((const float4*)h)[(((size_t)(r0 + row)) << 5) + qq];
    aT[4 * qq + 0][row] = v.x; aT[4 * qq + 1][row] = v.y;
    aT[4 * qq + 2][row] = v.z; aT[4 * qq + 3][row] = v.w;
    int wrow = c0 + row;
    float4 wv;
    if (wrow < NCLS) wv = ((const float4*)w_fc)[(((size_t)wrow) << 5) + qq];
    else { wv.x = 0.f; wv.y = 0.f; wv.z = 0.f; wv.w = 0.f; }
    bT[4 * qq + 0][row] = wv.x; bT[4 * qq + 1][row] = wv.y;
    bT[4 * qq + 2][row] = wv.z; bT[4 * qq + 3][row] = wv.w;
  }
  __syncthreads();

  const int cr = tid & 15, rr = tid >> 4;
  float acc[4][4];
#pragma unroll
  for (int i = 0; i < 4; i++)
#pragma unroll
    for (int j = 0; j < 4; j++) acc[i][j] = 0.0f;

#pragma unroll 4
  for (int k = 0; k < HID; k++) {
    float4 av = *(const float4*)&aT[k][4 * rr];
    float4 bv = *(const float4*)&bT[k][4 * cr];
    float a[4] = {av.x, av.y, av.z, av.w};
    float bb[4] = {bv.x, bv.y, bv.z, bv.w};
#pragma unroll
    for (int i = 0; i < 4; i++)
#pragma unroll
      for (int j = 0; j < 4; j++) acc[i][j] += a[i] * bb[j];
  }

#pragma unroll
  for (int j = 0; j < 4; j++) {
    int cc = c0 + 4 * cr + j;
    if (cc < NCLS) {
      float bias = b_fc[cc];
#pragma unroll
      for (int i = 0; i < 4; i++)
        out[(size_t)(r0 + 4 * rr + i) * NCLS + cc] = acc[i][j] + bias;
    }
  }
}

extern "C" void kernel_launch(void* const* d_in, const int* in_sizes, int n_in,
                              void* d_out, int out_size, void* d_ws, size_t ws_size,
                              hipStream_t stream) {
  const int*   xx   = (const int*)d_in[0];
  const float* emb  = (const float*)d_in[1];
  const float* w_ih = (const float*)d_in[2];
  const float* w_hh = (const float*)d_in[3];
  const float* b_ih = (const float*)d_in[4];
  const float* b_hh = (const float*)d_in[5];
  const float* w_fc = (const float*)d_in[6];
  const float* b_fc = (const float*)d_in[7];
  float* out = (float*)d_out;

  const size_t pbytes = (size_t)VOCAB * G4 * sizeof(ushort); // 51.5 MB
  const size_t palign = (pbytes + 255) & ~(size_t)255;
  const size_t hbytes = (size_t)BATCH * HID * sizeof(float);

  float* hout;
  if (ws_size >= palign + hbytes) {
    ushort* P2 = (ushort*)d_ws;
    hout = (float*)((char*)d_ws + palign);
    build_P<<<(VOCAB + VROWS - 1) / VROWS, 512, 0, stream>>>(emb, w_ih, b_ih, b_hh, P2);
    lstm_scan<true><<<BATCH, 512, 0, stream>>>(xx, emb, w_ih, w_hh, b_ih, b_hh, P2, hout);
  } else {
    hout = (float*)d_ws;
    lstm_scan<false><<<BATCH, 512, 0, stream>>>(xx, emb, w_ih, w_hh, b_ih, b_hh,
                                                (const ushort*)nullptr, hout);
  }
  dim3 fcg((NCLS + FCC - 1) / FCC, BATCH / FCR);
  fc_kernel<<<fcg, 256, 0, stream>>>(hout, w_fc, b_fc, out);
}

// Round 6
// 1017.129 us; speedup vs baseline: 1.2566x; 1.1480x over previous
//
#include <hip/hip_runtime.h>

#define DI __device__ __forceinline__

typedef unsigned int uint;
typedef unsigned short ushort;
typedef _Float16 half2t __attribute__((ext_vector_type(2)));

#define VOCAB 50257
#define NEMB 48
#define HID 128
#define G4 512
#define NCLS 2000
#define BATCH 512
#define SEQ 1024

#if __has_builtin(__builtin_amdgcn_fdot2)
DI float fdot2(half2t a, half2t b, float c) { return __builtin_amdgcn_fdot2(a, b, c, false); }
#else
DI float fdot2(half2t a, half2t b, float c) { return c + (float)a.x * (float)b.x + (float)a.y * (float)b.y; }
#endif

#define LOG2E 1.4426950408889634f

// DPP quad helpers (VALU pipe)
DI float dppx1(float v) {  // lane ^ 1
  return __builtin_bit_cast(float,
      __builtin_amdgcn_update_dpp(0, __builtin_bit_cast(int, v), 0xB1, 0xF, 0xF, true));
}
DI float dppx2(float v) {  // lane ^ 2
  return __builtin_bit_cast(float,
      __builtin_amdgcn_update_dpp(0, __builtin_bit_cast(int, v), 0x4E, 0xF, 0xF, true));
}
DI float dppb3(float v) {  // broadcast quad-lane 3
  return __builtin_bit_cast(float,
      __builtin_amdgcn_update_dpp(0, __builtin_bit_cast(int, v), 0xFF, 0xF, 0xF, true));
}

// ---------------------------------------------------------------------------
// Phase A: P3[v][g*128+u] = emb[v].w_ih[g*128+u] + b_ih + b_hh  (f16, natural
// gate-major order = w_ih row order; no repack needed).
// ---------------------------------------------------------------------------
#define VROWS 32
__global__ __launch_bounds__(512) void build_P(
    const float* __restrict__ emb, const float* __restrict__ w_ih,
    const float* __restrict__ b_ih, const float* __restrict__ b_hh,
    ushort* __restrict__ P3)
{
  __shared__ __align__(16) float eL[VROWS][NEMB];
  const int tid = threadIdx.x;
  const int v0 = blockIdx.x * VROWS;
  int nrows = VOCAB - v0; if (nrows > VROWS) nrows = VROWS;

  for (int f = tid; f < nrows * NEMB; f += 512)
    eL[f / NEMB][f % NEMB] = emb[(size_t)v0 * NEMB + f];

  float w[NEMB];
  {
    const float* wr = w_ih + (size_t)tid * NEMB;
#pragma unroll
    for (int k = 0; k < NEMB; k++) w[k] = wr[k];
  }
  float bias = b_ih[tid] + b_hh[tid];
  __syncthreads();

  for (int v = 0; v < nrows; v++) {
    const float4* e4 = (const float4*)&eL[v][0];
    float a = bias;
#pragma unroll
    for (int k = 0; k < NEMB / 4; k++) {
      float4 e = e4[k];
      a += w[4 * k] * e.x + w[4 * k + 1] * e.y + w[4 * k + 2] * e.z + w[4 * k + 3] * e.w;
    }
    P3[(size_t)(v0 + v) * G4 + tid] = __builtin_bit_cast(ushort, (_Float16)a);
  }
}

// ---------------------------------------------------------------------------
// Phase B: persistent LSTM scan. 512 blocks x 512 threads (1 row/block,
// 2 blocks/CU, 4 waves/SIMD). Thread (u=tid>>2, q=tid&3) dots unit u's 4 gate
// rows over k in [32q,32q+32) (64 fdot2, 4 broadcast ds_read_b128), then a
// cndmask-steered 2-stage DPP TRANSPOSE-reduce leaves gate q's full pre-act
// in lane q (no redundancy). Activation is unified sigma/tanh with per-lane
// constants: 2 trans ops/lane/step (was 10 redundant x4). c lives in lane 0
// of each quad; sigma_f, tanh(g), sigma_o routed by 3 quad-DPP ops.
// Double-buffered h16 -> 1 barrier/step. xg: one f16 gather from P3, 2-ahead.
// ---------------------------------------------------------------------------
template<bool USE_P>
__global__ __launch_bounds__(512, 4) void lstm_scan(
    const int* __restrict__ x, const float* __restrict__ emb,
    const float* __restrict__ w_ih, const float* __restrict__ w_hh,
    const float* __restrict__ b_ih, const float* __restrict__ b_hh,
    const ushort* __restrict__ P3, float* __restrict__ hout)
{
  __shared__ int tokL[SEQ];
  __shared__ __align__(16) _Float16 h16[2][HID];
  __shared__ __align__(8) half2t e16[2][NEMB / 2];

  const int tid = threadIdx.x;
  const int b   = blockIdx.x;
  const int u   = tid >> 2;        // unit
  const int q   = tid & 3;         // gate owned after reduce / k-quarter
  const bool par1 = (q & 1) != 0;
  const bool par2 = (q & 2) != 0;
  const int goff = (q << 7) + u;   // gate-major offset within a P3 row

  // unified activation constants: gates 0,1,3 sigmoid; gate 2 tanh
  const bool isg = (q == 2);
  const float mk = isg ? (2.0f * LOG2E) : (-LOG2E);
  const float av = isg ? -2.0f : 1.0f;
  const float bv = isg ? 1.0f : 0.0f;

  {
    const int* xp = x + (size_t)b * SEQ;
    tokL[tid] = xp[tid];
    tokL[tid + 512] = xp[tid + 512];
  }

  // W_hh fragments: gates i,f,g,o of unit u, k in [32q, 32q+32): 64 VGPRs.
  half2t w[4][16];
#pragma unroll
  for (int g = 0; g < 4; g++) {
    const float4* wr = (const float4*)(w_hh + (size_t)(g * HID + u) * HID + 32 * q);
#pragma unroll
    for (int k4 = 0; k4 < 8; k4++) {
      float4 v = wr[k4];
      half2t p;
      p.x = (_Float16)v.x; p.y = (_Float16)v.y; w[g][2 * k4] = p;
      p.x = (_Float16)v.z; p.y = (_Float16)v.w; w[g][2 * k4 + 1] = p;
    }
  }

  // Fallback: this lane's single gate row of w_ih (full K=48) + bias.
  half2t wihq[NEMB / 2];
  float biasq = 0.0f;
  if (!USE_P) {
    const float* wr = w_ih + (size_t)(q * HID + u) * NEMB;
#pragma unroll
    for (int k = 0; k < NEMB / 2; k++) {
      half2t p; p.x = (_Float16)wr[2 * k]; p.y = (_Float16)wr[2 * k + 1];
      wihq[k] = p;
    }
    biasq = b_ih[q * HID + u] + b_hh[q * HID + u];
  }
  if (tid < HID) h16[1][tid] = (_Float16)0.0f;   // step 0 reads buf 1
  __syncthreads();

  float c = 0.0f;
  ushort pa = 0, pb = 0;
  float2 einfl = {0.0f, 0.0f};
  if (USE_P) {
    pa = P3[(size_t)tokL[0] * G4 + goff];
    pb = P3[(size_t)tokL[1] * G4 + goff];
  } else {
    if (tid < NEMB / 2) {
      float2 e0 = ((const float2*)(emb + (size_t)tokL[0] * NEMB))[tid];
      einfl     = ((const float2*)(emb + (size_t)tokL[1] * NEMB))[tid];
      half2t p; p.x = (_Float16)e0.x; p.y = (_Float16)e0.y;
      e16[0][tid] = p;
    }
    __syncthreads();
  }

#define STEP(t, par) do {                                                      \
    int tc = (t) + 2; if (tc > SEQ - 1) tc = SEQ - 1;                          \
    int tn = tokL[tc];                                                         \
    ushort cur = (par) ? pb : pa;                                              \
    if (USE_P) {                                                               \
      ushort nx = P3[(size_t)tn * G4 + goff]; /* prefetch t+2 */               \
      if ((par) == 0) pa = nx; else pb = nx;                                   \
    } else {                                                                   \
      if (tid < NEMB / 2) {                                                    \
        half2t p; p.x = (_Float16)einfl.x; p.y = (_Float16)einfl.y;            \
        e16[((t) + 1) & 1][tid] = p;                                           \
        einfl = ((const float2*)(emb + (size_t)tn * NEMB))[tid];               \
      }                                                                        \
    }                                                                          \
    const uint4* hv = (const uint4*)(&h16[(par) ^ 1][32 * q]);                 \
    float a0 = 0.f, a1 = 0.f, a2 = 0.f, a3 = 0.f;                              \
    _Pragma("unroll")                                                          \
    for (int q4 = 0; q4 < 4; q4++) {                                           \
      uint4 hq = hv[q4];                                                       \
      half2t h0 = __builtin_bit_cast(half2t, hq.x);                            \
      half2t h1 = __builtin_bit_cast(half2t, hq.y);                            \
      half2t h2 = __builtin_bit_cast(half2t, hq.z);                            \
      half2t h3 = __builtin_bit_cast(half2t, hq.w);                            \
      a0 = fdot2(w[0][4*q4+0], h0, a0); a1 = fdot2(w[1][4*q4+0], h0, a1);      \
      a2 = fdot2(w[2][4*q4+0], h0, a2); a3 = fdot2(w[3][4*q4+0], h0, a3);      \
      a0 = fdot2(w[0][4*q4+1], h1, a0); a1 = fdot2(w[1][4*q4+1], h1, a1);      \
      a2 = fdot2(w[2][4*q4+1], h1, a2); a3 = fdot2(w[3][4*q4+1], h1, a3);      \
      a0 = fdot2(w[0][4*q4+2], h2, a0); a1 = fdot2(w[1][4*q4+2], h2, a1);      \
      a2 = fdot2(w[2][4*q4+2], h2, a2); a3 = fdot2(w[3][4*q4+2], h2, a3);      \
      a0 = fdot2(w[0][4*q4+3], h3, a0); a1 = fdot2(w[1][4*q4+3], h3, a1);      \
      a2 = fdot2(w[2][4*q4+3], h3, a2); a3 = fdot2(w[3][4*q4+3], h3, a3);      \
    }                                                                          \
    /* transpose-reduce: lane q <- full pre-act of gate q */                   \
    float kA = par1 ? a1 : a0, sA = par1 ? a0 : a1; kA += dppx1(sA);           \
    float kB = par1 ? a3 : a2, sB = par1 ? a2 : a3; kB += dppx1(sB);           \
    float kF = par2 ? kB : kA, sF = par2 ? kA : kB; kF += dppx2(sF);           \
    float xg;                                                                  \
    if (USE_P) {                                                               \
      xg = (float)__builtin_bit_cast(_Float16, cur);                           \
    } else {                                                                   \
      xg = biasq;                                                              \
      _Pragma("unroll")                                                        \
      for (int k = 0; k < NEMB / 2; k++) xg = fdot2(wihq[k], e16[(par)][k], xg);\
    }                                                                          \
    float gv = kF + xg;                                                        \
    float act = av * __builtin_amdgcn_rcpf(                                    \
                    __builtin_amdgcn_exp2f(mk * gv) + 1.0f) + bv;              \
    float gt = dppx2(act);          /* lane0: tanh(g) */                       \
    float sf = dppx1(act);          /* lane0: sigma(f) */                      \
    c = act * gt + sf * c;          /* valid in lane 0 */                      \
    float tanhc = 1.0f - 2.0f * __builtin_amdgcn_rcpf(                         \
                    __builtin_amdgcn_exp2f(2.0f * LOG2E * c) + 1.0f);          \
    float so = dppb3(act);          /* sigma(o) everywhere */                  \
    float hh = so * tanhc;          /* valid in lane 0 */                      \
    if (q == 0) {                                                              \
      h16[(par)][u] = (_Float16)hh;                                            \
      if ((t) == SEQ - 1) hout[(size_t)b * HID + u] = hh;                      \
    }                                                                          \
    __syncthreads();                                                           \
  } while (0)

  for (int t = 0; t < SEQ; t += 2) { STEP(t, 0); STEP(t + 1, 1); }
#undef STEP
}

// ---------------------------------------------------------------------------
// Phase C: FC  out[512,2000] = h[512,128] @ w_fc^T + b_fc.  64x64 tiles.
// ---------------------------------------------------------------------------
#define FCR 64
#define FCC 64
__global__ __launch_bounds__(256) void fc_kernel(
    const float* __restrict__ h, const float* __restrict__ w_fc,
    const float* __restrict__ b_fc, float* __restrict__ out)
{
  __shared__ float aT[HID][FCR];
  __shared__ float bT[HID][FCC];
  const int tid = threadIdx.x;
  const int r0 = blockIdx.y * FCR;
  const int c0 = blockIdx.x * FCC;

  for (int f = tid; f < FCR * (HID / 4); f += 256) {
    int row = f >> 5, qq = f & 31;
    float4 v = ((const float4*)h)[(((size_t)(r0 + row)) << 5) + qq];
    aT[4 * qq + 0][row] = v.x; aT[4 * qq + 1][row] = v.y;
    aT[4 * qq + 2][row] = v.z; aT[4 * qq + 3][row] = v.w;
    int wrow = c0 + row;
    float4 wv;
    if (wrow < NCLS) wv = ((const float4*)w_fc)[(((size_t)wrow) << 5) + qq];
    else { wv.x = 0.f; wv.y = 0.f; wv.z = 0.f; wv.w = 0.f; }
    bT[4 * qq + 0][row] = wv.x; bT[4 * qq + 1][row] = wv.y;
    bT[4 * qq + 2][row] = wv.z; bT[4 * qq + 3][row] = wv.w;
  }
  __syncthreads();

  const int cr = tid & 15, rr = tid >> 4;
  float acc[4][4];
#pragma unroll
  for (int i = 0; i < 4; i++)
#pragma unroll
    for (int j = 0; j < 4; j++) acc[i][j] = 0.0f;

#pragma unroll 4
  for (int k = 0; k < HID; k++) {
    float4 av = *(const float4*)&aT[k][4 * rr];
    float4 bv = *(const float4*)&bT[k][4 * cr];
    float a[4] = {av.x, av.y, av.z, av.w};
    float bb[4] = {bv.x, bv.y, bv.z, bv.w};
#pragma unroll
    for (int i = 0; i < 4; i++)
#pragma unroll
      for (int j = 0; j < 4; j++) acc[i][j] += a[i] * bb[j];
  }

#pragma unroll
  for (int j = 0; j < 4; j++) {
    int cc = c0 + 4 * cr + j;
    if (cc < NCLS) {
      float bias = b_fc[cc];
#pragma unroll
      for (int i = 0; i < 4; i++)
        out[(size_t)(r0 + 4 * rr + i) * NCLS + cc] = acc[i][j] + bias;
    }
  }
}

extern "C" void kernel_launch(void* const* d_in, const int* in_sizes, int n_in,
                              void* d_out, int out_size, void* d_ws, size_t ws_size,
                              hipStream_t stream) {
  const int*   xx   = (const int*)d_in[0];
  const float* emb  = (const float*)d_in[1];
  const float* w_ih = (const float*)d_in[2];
  const float* w_hh = (const float*)d_in[3];
  const float* b_ih = (const float*)d_in[4];
  const float* b_hh = (const float*)d_in[5];
  const float* w_fc = (const float*)d_in[6];
  const float* b_fc = (const float*)d_in[7];
  float* out = (float*)d_out;

  const size_t pbytes = (size_t)VOCAB * G4 * sizeof(ushort); // 51.5 MB
  const size_t palign = (pbytes + 255) & ~(size_t)255;
  const size_t hbytes = (size_t)BATCH * HID * sizeof(float);

  float* hout;
  if (ws_size >= palign + hbytes) {
    ushort* P3 = (ushort*)d_ws;
    hout = (float*)((char*)d_ws + palign);
    build_P<<<(VOCAB + VROWS - 1) / VROWS, 512, 0, stream>>>(emb, w_ih, b_ih, b_hh, P3);
    lstm_scan<true><<<BATCH, 512, 0, stream>>>(xx, emb, w_ih, w_hh, b_ih, b_hh, P3, hout);
  } else {
    hout = (float*)d_ws;
    lstm_scan<false><<<BATCH, 512, 0, stream>>>(xx, emb, w_ih, w_hh, b_ih, b_hh,
                                                (const ushort*)nullptr, hout);
  }
  dim3 fcg((NCLS + FCC - 1) / FCC, BATCH / FCR);
  fc_kernel<<<fcg, 256, 0, stream>>>(hout, w_fc, b_fc, out);
}

// Round 7
// 1004.131 us; speedup vs baseline: 1.2728x; 1.0129x over previous
//
#include <hip/hip_runtime.h>

#define DI __device__ __forceinline__

typedef unsigned int uint;
typedef unsigned short ushort;
typedef _Float16 half2t __attribute__((ext_vector_type(2)));

#define VOCAB 50257
#define NEMB 48
#define HID 128
#define G4 512
#define NCLS 2000
#define BATCH 512
#define SEQ 1024

#if __has_builtin(__builtin_amdgcn_fdot2)
DI float fdot2(half2t a, half2t b, float c) { return __builtin_amdgcn_fdot2(a, b, c, false); }
#else
DI float fdot2(half2t a, half2t b, float c) { return c + (float)a.x * (float)b.x + (float)a.y * (float)b.y; }
#endif

#define LOG2E 1.4426950408889634f

// DPP quad helpers (VALU pipe)
DI float dppx1(float v) {  // lane ^ 1
  return __builtin_bit_cast(float,
      __builtin_amdgcn_update_dpp(0, __builtin_bit_cast(int, v), 0xB1, 0xF, 0xF, true));
}
DI float dppx2(float v) {  // lane ^ 2
  return __builtin_bit_cast(float,
      __builtin_amdgcn_update_dpp(0, __builtin_bit_cast(int, v), 0x4E, 0xF, 0xF, true));
}
DI float dppb3(float v) {  // broadcast quad-lane 3
  return __builtin_bit_cast(float,
      __builtin_amdgcn_update_dpp(0, __builtin_bit_cast(int, v), 0xFF, 0xF, 0xF, true));
}

// LDS-only barrier: orders LDS (lgkm) across the block WITHOUT draining vmcnt,
// so in-flight global prefetches survive the barrier (AITER-style pipeline).
// __syncthreads() would emit s_waitcnt vmcnt(0) before s_barrier and put the
// P3 gather latency on every step's critical path.
DI void bar_lds() { asm volatile("s_waitcnt lgkmcnt(0)\n\ts_barrier" ::: "memory"); }

// ---------------------------------------------------------------------------
// Phase A: P3[v][g*128+u] = emb[v].w_ih[g*128+u] + b_ih + b_hh  (f16, natural
// gate-major order = w_ih row order; no repack needed).
// ---------------------------------------------------------------------------
#define VROWS 32
__global__ __launch_bounds__(512) void build_P(
    const float* __restrict__ emb, const float* __restrict__ w_ih,
    const float* __restrict__ b_ih, const float* __restrict__ b_hh,
    ushort* __restrict__ P3)
{
  __shared__ __align__(16) float eL[VROWS][NEMB];
  const int tid = threadIdx.x;
  const int v0 = blockIdx.x * VROWS;
  int nrows = VOCAB - v0; if (nrows > VROWS) nrows = VROWS;

  for (int f = tid; f < nrows * NEMB; f += 512)
    eL[f / NEMB][f % NEMB] = emb[(size_t)v0 * NEMB + f];

  float w[NEMB];
  {
    const float* wr = w_ih + (size_t)tid * NEMB;
#pragma unroll
    for (int k = 0; k < NEMB; k++) w[k] = wr[k];
  }
  float bias = b_ih[tid] + b_hh[tid];
  __syncthreads();

  for (int v = 0; v < nrows; v++) {
    const float4* e4 = (const float4*)&eL[v][0];
    float a = bias;
#pragma unroll
    for (int k = 0; k < NEMB / 4; k++) {
      float4 e = e4[k];
      a += w[4 * k] * e.x + w[4 * k + 1] * e.y + w[4 * k + 2] * e.z + w[4 * k + 3] * e.w;
    }
    P3[(size_t)(v0 + v) * G4 + tid] = __builtin_bit_cast(ushort, (_Float16)a);
  }
}

// ---------------------------------------------------------------------------
// Phase B: persistent LSTM scan. 512 blocks x 512 threads (1 row/block,
// 2 blocks/CU, 4 waves/SIMD). Thread (u=tid>>2, q=tid&3) dots unit u's 4 gate
// rows over k in [32q,32q+32) (64 fdot2, 4 broadcast ds_read_b128), then a
// cndmask-steered 2-stage DPP transpose-reduce leaves gate q's pre-act in
// lane q. Unified sigma/tanh (2 trans/lane/step). c lives in lane 0 of each
// quad. LDS-only barrier (no vmcnt drain) + 4-deep P3 prefetch pipeline.
// ---------------------------------------------------------------------------
template<bool USE_P>
__global__ __launch_bounds__(512, 4) void lstm_scan(
    const int* __restrict__ x, const float* __restrict__ emb,
    const float* __restrict__ w_ih, const float* __restrict__ w_hh,
    const float* __restrict__ b_ih, const float* __restrict__ b_hh,
    const ushort* __restrict__ P3, float* __restrict__ hout)
{
  __shared__ int tokPad[SEQ + 4];
  __shared__ __align__(16) _Float16 h16[2][HID];
  __shared__ __align__(8) half2t e16[2][NEMB / 2];

  const int tid = threadIdx.x;
  const int b   = blockIdx.x;
  const int u   = tid >> 2;        // unit
  const int q   = tid & 3;         // gate owned after reduce / k-quarter
  const bool par1 = (q & 1) != 0;
  const bool par2 = (q & 2) != 0;
  const int goff = (q << 7) + u;   // gate-major offset within a P3 row

  // unified activation constants: gates 0,1,3 sigmoid; gate 2 tanh
  const bool isg = (q == 2);
  const float mk = isg ? (2.0f * LOG2E) : (-LOG2E);
  const float av = isg ? -2.0f : 1.0f;
  const float bv = isg ? 1.0f : 0.0f;

  {
    const int* xp = x + (size_t)b * SEQ;
    tokPad[tid] = xp[tid];
    tokPad[tid + 512] = xp[tid + 512];
    if (tid < 4) tokPad[SEQ + tid] = xp[SEQ - 1];
  }

  // W_hh fragments: gates i,f,g,o of unit u, k in [32q, 32q+32): 64 VGPRs.
  half2t w[4][16];
#pragma unroll
  for (int g = 0; g < 4; g++) {
    const float4* wr = (const float4*)(w_hh + (size_t)(g * HID + u) * HID + 32 * q);
#pragma unroll
    for (int k4 = 0; k4 < 8; k4++) {
      float4 v = wr[k4];
      half2t p;
      p.x = (_Float16)v.x; p.y = (_Float16)v.y; w[g][2 * k4] = p;
      p.x = (_Float16)v.z; p.y = (_Float16)v.w; w[g][2 * k4 + 1] = p;
    }
  }

  // Fallback: this lane's single gate row of w_ih (full K=48) + bias.
  half2t wihq[NEMB / 2];
  float biasq = 0.0f;
  if (!USE_P) {
    const float* wr = w_ih + (size_t)(q * HID + u) * NEMB;
#pragma unroll
    for (int k = 0; k < NEMB / 2; k++) {
      half2t p; p.x = (_Float16)wr[2 * k]; p.y = (_Float16)wr[2 * k + 1];
      wihq[k] = p;
    }
    biasq = b_ih[q * HID + u] + b_hh[q * HID + u];
  }
  if (tid < HID) h16[1][tid] = (_Float16)0.0f;   // step 0 reads buf 1
  __syncthreads();  // init barrier (full drain once is fine)

  float c = 0.0f;
  ushort pr0 = 0, pr1 = 0, pr2 = 0, pr3 = 0;
  float2 einfl = {0.0f, 0.0f};
  if (USE_P) {
    pr0 = P3[(size_t)tokPad[0] * G4 + goff];
    pr1 = P3[(size_t)tokPad[1] * G4 + goff];
    pr2 = P3[(size_t)tokPad[2] * G4 + goff];
    pr3 = P3[(size_t)tokPad[3] * G4 + goff];
  } else {
    if (tid < NEMB / 2) {
      float2 e0 = ((const float2*)(emb + (size_t)tokPad[0] * NEMB))[tid];
      einfl     = ((const float2*)(emb + (size_t)tokPad[1] * NEMB))[tid];
      half2t p; p.x = (_Float16)e0.x; p.y = (_Float16)e0.y;
      e16[0][tid] = p;
    }
    __syncthreads();
  }

// One timestep; tt = t + jpar, jpar is a 0..3 literal, PRJ names the
// prefetch register for this phase (consumed now, refilled for tt+4).
#define STEP(tt, jpar, PRJ) do {                                               \
    ushort cur = PRJ;                                                          \
    if (USE_P) {                                                               \
      int tn4 = tokPad[(tt) + 4];                                              \
      PRJ = P3[(size_t)tn4 * G4 + goff];   /* prefetch t+4, no drain */        \
    } else {                                                                   \
      if (tid < NEMB / 2) {                                                    \
        half2t p; p.x = (_Float16)einfl.x; p.y = (_Float16)einfl.y;            \
        e16[((tt) + 1) & 1][tid] = p;                                          \
        einfl = ((const float2*)(emb + (size_t)tokPad[(tt) + 2] * NEMB))[tid]; \
      }                                                                        \
    }                                                                          \
    const uint4* hv = (const uint4*)(&h16[((jpar) + 1) & 1][32 * q]);          \
    float a0 = 0.f, a1 = 0.f, a2 = 0.f, a3 = 0.f;                              \
    _Pragma("unroll")                                                          \
    for (int q4 = 0; q4 < 4; q4++) {                                           \
      uint4 hq = hv[q4];                                                       \
      half2t h0 = __builtin_bit_cast(half2t, hq.x);                            \
      half2t h1 = __builtin_bit_cast(half2t, hq.y);                            \
      half2t h2 = __builtin_bit_cast(half2t, hq.z);                            \
      half2t h3 = __builtin_bit_cast(half2t, hq.w);                            \
      a0 = fdot2(w[0][4*q4+0], h0, a0); a1 = fdot2(w[1][4*q4+0], h0, a1);      \
      a2 = fdot2(w[2][4*q4+0], h0, a2); a3 = fdot2(w[3][4*q4+0], h0, a3);      \
      a0 = fdot2(w[0][4*q4+1], h1, a0); a1 = fdot2(w[1][4*q4+1], h1, a1);      \
      a2 = fdot2(w[2][4*q4+1], h1, a2); a3 = fdot2(w[3][4*q4+1], h1, a3);      \
      a0 = fdot2(w[0][4*q4+2], h2, a0); a1 = fdot2(w[1][4*q4+2], h2, a1);      \
      a2 = fdot2(w[2][4*q4+2], h2, a2); a3 = fdot2(w[3][4*q4+2], h2, a3);      \
      a0 = fdot2(w[0][4*q4+3], h3, a0); a1 = fdot2(w[1][4*q4+3], h3, a1);      \
      a2 = fdot2(w[2][4*q4+3], h3, a2); a3 = fdot2(w[3][4*q4+3], h3, a3);      \
    }                                                                          \
    /* transpose-reduce: lane q <- full pre-act of gate q */                   \
    float kA = par1 ? a1 : a0, sA = par1 ? a0 : a1; kA += dppx1(sA);           \
    float kB = par1 ? a3 : a2, sB = par1 ? a2 : a3; kB += dppx1(sB);           \
    float kF = par2 ? kB : kA, sF = par2 ? kA : kB; kF += dppx2(sF);           \
    float xg;                                                                  \
    if (USE_P) {                                                               \
      xg = (float)__builtin_bit_cast(_Float16, cur);                           \
    } else {                                                                   \
      xg = biasq;                                                              \
      _Pragma("unroll")                                                        \
      for (int k = 0; k < NEMB / 2; k++)                                       \
        xg = fdot2(wihq[k], e16[(jpar) & 1][k], xg);                           \
    }                                                                          \
    float gv = kF + xg;                                                        \
    float act = av * __builtin_amdgcn_rcpf(                                    \
                    __builtin_amdgcn_exp2f(mk * gv) + 1.0f) + bv;              \
    float gt = dppx2(act);          /* lane0: tanh(g) */                       \
    float sf = dppx1(act);          /* lane0: sigma(f) */                      \
    c = act * gt + sf * c;          /* valid in lane 0 */                      \
    float tanhc = 1.0f - 2.0f * __builtin_amdgcn_rcpf(                         \
                    __builtin_amdgcn_exp2f(2.0f * LOG2E * c) + 1.0f);          \
    float so = dppb3(act);          /* sigma(o) everywhere */                  \
    float hh = so * tanhc;          /* valid in lane 0 */                      \
    if (q == 0) {                                                              \
      h16[(jpar) & 1][u] = (_Float16)hh;                                       \
      if ((tt) == SEQ - 1) hout[(size_t)b * HID + u] = hh;                     \
    }                                                                          \
    bar_lds();                                                                 \
  } while (0)

  for (int t = 0; t < SEQ; t += 4) {
    STEP(t, 0, pr0);
    STEP(t + 1, 1, pr1);
    STEP(t + 2, 2, pr2);
    STEP(t + 3, 3, pr3);
  }
#undef STEP
}

// ---------------------------------------------------------------------------
// Phase C: FC  out[512,2000] = h[512,128] @ w_fc^T + b_fc.  64x64 tiles.
// ---------------------------------------------------------------------------
#define FCR 64
#define FCC 64
__global__ __launch_bounds__(256) void fc_kernel(
    const float* __restrict__ h, const float* __restrict__ w_fc,
    const float* __restrict__ b_fc, float* __restrict__ out)
{
  __shared__ float aT[HID][FCR];
  __shared__ float bT[HID][FCC];
  const int tid = threadIdx.x;
  const int r0 = blockIdx.y * FCR;
  const int c0 = blockIdx.x * FCC;

  for (int f = tid; f < FCR * (HID / 4); f += 256) {
    int row = f >> 5, qq = f & 31;
    float4 v = ((const float4*)h)[(((size_t)(r0 + row)) << 5) + qq];
    aT[4 * qq + 0][row] = v.x; aT[4 * qq + 1][row] = v.y;
    aT[4 * qq + 2][row] = v.z; aT[4 * qq + 3][row] = v.w;
    int wrow = c0 + row;
    float4 wv;
    if (wrow < NCLS) wv = ((const float4*)w_fc)[(((size_t)wrow) << 5) + qq];
    else { wv.x = 0.f; wv.y = 0.f; wv.z = 0.f; wv.w = 0.f; }
    bT[4 * qq + 0][row] = wv.x; bT[4 * qq + 1][row] = wv.y;
    bT[4 * qq + 2][row] = wv.z; bT[4 * qq + 3][row] = wv.w;
  }
  __syncthreads();

  const int cr = tid & 15, rr = tid >> 4;
  float acc[4][4];
#pragma unroll
  for (int i = 0; i < 4; i++)
#pragma unroll
    for (int j = 0; j < 4; j++) acc[i][j] = 0.0f;

#pragma unroll 4
  for (int k = 0; k < HID; k++) {
    float4 av = *(const float4*)&aT[k][4 * rr];
    float4 bv = *(const float4*)&bT[k][4 * cr];
    float a[4] = {av.x, av.y, av.z, av.w};
    float bb[4] = {bv.x, bv.y, bv.z, bv.w};
#pragma unroll
    for (int i = 0; i < 4; i++)
#pragma unroll
      for (int j = 0; j < 4; j++) acc[i][j] += a[i] * bb[j];
  }

#pragma unroll
  for (int j = 0; j < 4; j++) {
    int cc = c0 + 4 * cr + j;
    if (cc < NCLS) {
      float bias = b_fc[cc];
#pragma unroll
      for (int i = 0; i < 4; i++)
        out[(size_t)(r0 + 4 * rr + i) * NCLS + cc] = acc[i][j] + bias;
    }
  }
}

extern "C" void kernel_launch(void* const* d_in, const int* in_sizes, int n_in,
                              void* d_out, int out_size, void* d_ws, size_t ws_size,
                              hipStream_t stream) {
  const int*   xx   = (const int*)d_in[0];
  const float* emb  = (const float*)d_in[1];
  const float* w_ih = (const float*)d_in[2];
  const float* w_hh = (const float*)d_in[3];
  const float* b_ih = (const float*)d_in[4];
  const float* b_hh = (const float*)d_in[5];
  const float* w_fc = (const float*)d_in[6];
  const float* b_fc = (const float*)d_in[7];
  float* out = (float*)d_out;

  const size_t pbytes = (size_t)VOCAB * G4 * sizeof(ushort); // 51.5 MB
  const size_t palign = (pbytes + 255) & ~(size_t)255;
  const size_t hbytes = (size_t)BATCH * HID * sizeof(float);

  float* hout;
  if (ws_size >= palign + hbytes) {
    ushort* P3 = (ushort*)d_ws;
    hout = (float*)((char*)d_ws + palign);
    build_P<<<(VOCAB + VROWS - 1) / VROWS, 512, 0, stream>>>(emb, w_ih, b_ih, b_hh, P3);
    lstm_scan<true><<<BATCH, 512, 0, stream>>>(xx, emb, w_ih, w_hh, b_ih, b_hh, P3, hout);
  } else {
    hout = (float*)d_ws;
    lstm_scan<false><<<BATCH, 512, 0, stream>>>(xx, emb, w_ih, w_hh, b_ih, b_hh,
                                                (const ushort*)nullptr, hout);
  }
  dim3 fcg((NCLS + FCC - 1) / FCC, BATCH / FCR);
  fc_kernel<<<fcg, 256, 0, stream>>>(hout, w_fc, b_fc, out);
}